// Round 18
// baseline (2397.193 us; speedup 1.0000x reference)
//
#include <hip/hip_runtime.h>
#include <stdint.h>

typedef unsigned short u16;
typedef unsigned int   u32;
typedef __bf16 bf16x8 __attribute__((ext_vector_type(8)));
typedef float  f32x4  __attribute__((ext_vector_type(4)));
typedef u16    u16x8  __attribute__((ext_vector_type(8)));
typedef u32    u32x2  __attribute__((ext_vector_type(2)));
typedef u32    u32x4  __attribute__((ext_vector_type(4)));

#define TBROWS 32704   // 511 * 64 valid (t,b) rows

__device__ __forceinline__ u16 f2bf(float f) {
  union { float f; u32 u; } v; v.f = f;
  u32 r = v.u + 0x7FFFu + ((v.u >> 16) & 1u);   // RNE
  return (u16)(r >> 16);
}
__device__ __forceinline__ float bf2f(u16 h) {
  union { u32 u; float f; } v; v.u = ((u32)h) << 16;
  return v.f;
}
__device__ __forceinline__ float fsigmoid(float x) {
  return 1.0f / (1.0f + exp2f(-1.44269504f * x));
}
__device__ __forceinline__ float ftanh(float x) {
  return 2.0f / (1.0f + exp2f(-2.88539008f * x)) - 1.0f;
}
__device__ __forceinline__ u32 pkmaxu16(u32 a, u32 b) {
  u32 d;
  asm("v_pk_max_u16 %0, %1, %2" : "=v"(d) : "v"(a), "v"(b));
  return d;
}
// valid h (|h|<1 -> u16 code <= 0xBF80); sentinel 0xFFFF. fresh <=> all halves < 0xC000
__device__ __forceinline__ int vec_fresh(u32x4 v) {
  u32 m = pkmaxu16(pkmaxu16(v[0], v[1]), pkmaxu16(v[2], v[3]));
  return (m < 0xC0000000u) && ((m << 16) < 0xC0000000u);
}

// ---------------- conversions ----------------

// x f32 [64][512][1024] -> bf16 same layout
__global__ __launch_bounds__(256) void conv_x(const float* __restrict__ x,
                                              u16* __restrict__ xb) {
  const int n4 = (64 * 512 * 1024) / 4;
  const float4* xv = (const float4*)x;
  for (int i = blockIdx.x * 256 + threadIdx.x; i < n4; i += 4096 * 256) {
    float4 v = xv[i];
    uint2 o;
    o.x = (u32)f2bf(v.x) | ((u32)f2bf(v.y) << 16);
    o.y = (u32)f2bf(v.z) | ((u32)f2bf(v.w) << 16);
    *(uint2*)(xb + (size_t)i * 4) = o;
  }
}

// Build UbT bf16 [4096][1024]: UbT[n][k] = U_g[k][hc], n = hc*4 + g (gate-interleaved)
__global__ __launch_bounds__(256) void conv_u(const float* __restrict__ U0,
                                              const float* __restrict__ U1,
                                              const float* __restrict__ U2,
                                              const float* __restrict__ U3,
                                              u16* __restrict__ UbT) {
  __shared__ float tile[64][65];
  const int bid = blockIdx.x;
  const int g = bid >> 8, kt = (bid >> 4) & 15, ht = bid & 15;
  const float* U = (g == 0) ? U0 : (g == 1) ? U1 : (g == 2) ? U2 : U3;
  const int t = threadIdx.x;
  const int c = t & 63, r0 = t >> 6;
#pragma unroll
  for (int rr = 0; rr < 64; rr += 4)
    tile[rr + r0][c] = U[(size_t)(kt * 64 + rr + r0) * 1024 + ht * 64 + c];
  __syncthreads();
  const int hcl = t >> 2, ks = t & 3;
  const int n = (ht * 64 + hcl) * 4 + g;
  u16x8 o0, o1;
#pragma unroll
  for (int ii = 0; ii < 8; ++ii) o0[ii] = f2bf(tile[ks * 16 + ii][hcl]);
#pragma unroll
  for (int ii = 0; ii < 8; ++ii) o1[ii] = f2bf(tile[ks * 16 + 8 + ii][hcl]);
  size_t base = (size_t)n * 1024 + kt * 64 + ks * 16;
  *(u16x8*)(UbT + base) = o0;
  *(u16x8*)(UbT + base + 8) = o1;
}

// bb f32 [4096] gate-interleaved: bb[hc*4+g] = b_g[hc]
__global__ __launch_bounds__(256) void conv_b(const float* __restrict__ b0,
                                              const float* __restrict__ b1,
                                              const float* __restrict__ b2,
                                              const float* __restrict__ b3,
                                              float* __restrict__ bb) {
  int n = blockIdx.x * 256 + threadIdx.x;
  if (n < 4096) {
    int g = n & 3, hc = n >> 2;
    const float* B = (g == 0) ? b0 : (g == 1) ? b1 : (g == 2) ? b2 : b3;
    bb[n] = B[hc];
  }
}

// sentinel-fill hseq (511 slots x 128KB) + zero spread flags (replay-safe)
__global__ __launch_bounds__(256) void init_sent(u32* __restrict__ p,
                                                 int* __restrict__ flags) {
  if (blockIdx.x == 0) flags[threadIdx.x * 32] = 0;   // 256 flags, 128B apart
  const size_t n4 = 4186112;   // uint4 count = 511*65536*2B / 16
  uint4 s = make_uint4(0xFFFFFFFFu, 0xFFFFFFFFu, 0xFFFFFFFFu, 0xFFFFFFFFu);
  for (size_t i = blockIdx.x * 256 + threadIdx.x; i < n4; i += (size_t)2048 * 256)
    *(uint4*)(p + i * 4) = s;
}

// ---------------- phase 1: x_proj GEMM ----------------
// xp[hc][tb][g] = sum_k UbT[hc*4+g][k] * xb[tb][k] + bb  (bf16 out)
// XCD-aware grid swizzle (T1): each XCD sweeps full nt rows per tt.
__global__ __launch_bounds__(256, 2) void gemm_xproj(const u16* __restrict__ xb,
                                                     const u16* __restrict__ UbT,
                                                     const float* __restrict__ bb,
                                                     u16* __restrict__ xp) {
  __shared__ __align__(16) u16 As[128 * 32];
  __shared__ __align__(16) u16 Bs[128 * 32];
  const int tid = threadIdx.x;
  const int lane = tid & 63, w = tid >> 6;
  const int q = lane >> 4, r15 = lane & 15;
  const int bid = (blockIdx.x & 7) * 1024 + (blockIdx.x >> 3);  // bijective (8192=8*1024)
  const int nt = bid & 31;               // M (n) tile
  const int tt = bid >> 5;               // N (tb) tile
  const int n_base = nt * 128;
  const long long tb_base = (long long)tt * 128;
  const int mh = w & 1, nh = w >> 1;

  f32x4 acc[4][4];
#pragma unroll
  for (int a = 0; a < 4; ++a)
#pragma unroll
    for (int b2 = 0; b2 < 4; ++b2) acc[a][b2] = (f32x4){0.f, 0.f, 0.f, 0.f};

#pragma unroll 1
  for (int kb = 0; kb < 32; ++kb) {
    __syncthreads();
    const int k0 = kb * 32;
#pragma unroll
    for (int call = 0; call < 2; ++call) {
      const int chunk = call * 256 + w * 64 + lane;
      const int row = chunk >> 2, q4 = chunk & 3;
      const u16* ga = UbT + (size_t)(n_base + row) * 1024 + k0 + q4 * 8;
      __builtin_amdgcn_global_load_lds(
          (const __attribute__((address_space(1))) void*)ga,
          (__attribute__((address_space(3))) void*)(As + (call * 256 + w * 64) * 8),
          16, 0, 0);
      long long tbr = tb_base + row;
      if (tbr > TBROWS - 1) tbr = TBROWS - 1;
      const int xbrow = ((int)tbr & 63) * 512 + ((int)tbr >> 6);  // (b,t) -> x row
      const u16* gb = xb + (size_t)xbrow * 1024 + k0 + q4 * 8;
      __builtin_amdgcn_global_load_lds(
          (const __attribute__((address_space(1))) void*)gb,
          (__attribute__((address_space(3))) void*)(Bs + (call * 256 + w * 64) * 8),
          16, 0, 0);
    }
    __syncthreads();
    bf16x8 af[4], bfr[4];
#pragma unroll
    for (int m = 0; m < 4; ++m)
      af[m] = *(const bf16x8*)(As + ((mh * 64 + m * 16 + r15) * 32 + q * 8));
#pragma unroll
    for (int n2 = 0; n2 < 4; ++n2)
      bfr[n2] = *(const bf16x8*)(Bs + ((nh * 64 + n2 * 16 + r15) * 32 + q * 8));
#pragma unroll
    for (int m = 0; m < 4; ++m)
#pragma unroll
      for (int n2 = 0; n2 < 4; ++n2)
        acc[m][n2] = __builtin_amdgcn_mfma_f32_16x16x32_bf16(af[m], bfr[n2],
                                                             acc[m][n2], 0, 0, 0);
  }
#pragma unroll
  for (int m = 0; m < 4; ++m) {
    const int nrow = n_base + mh * 64 + m * 16 + q * 4;
    const float4 bias = *(const float4*)(bb + nrow);
    const long long hcb = (long long)(nrow >> 2) * TBROWS;
#pragma unroll
    for (int n2 = 0; n2 < 4; ++n2) {
      const long long tb = tb_base + nh * 64 + n2 * 16 + r15;
      if (tb < TBROWS) {
        const f32x4 v = acc[m][n2];
        uint2 pk;
        pk.x = (u32)f2bf(v[0] + bias.x) | ((u32)f2bf(v[1] + bias.y) << 16);
        pk.y = (u32)f2bf(v[2] + bias.z) | ((u32)f2bf(v[3] + bias.w) << 16);
        *(uint2*)(xp + (hcb + tb) * 4) = pk;
      }
    }
  }
}

// ---------------- phase 2: persistent recurrence ----------------
// R17 (1490us) with ONE isolated change: SPECULATIVE FIRST DATA PASS —
// consumers issue the 8 data loads BEFORE consulting the flag (write-once
// slots + in-band sentinel validation make this safe; consumer-side remote
// reads don't perturb producer-side store visibility, unlike the banned
// producer pre-touch). All-fresh => flag read skipped entirely (saves ~1 RT).
// Stale subset => flag-gated bounded retry (only slow producers re-read).
__global__ __launch_bounds__(256, 1) void lstm_rec(
    const float* __restrict__ V0, const float* __restrict__ V1,
    const float* __restrict__ V2, const float* __restrict__ V3,
    const u16* __restrict__ xp, u16* hseq, int* flags, float* __restrict__ out) {
  __shared__ __align__(16) f32x4 part[2][4][4][64];   // [parity][wave][tile][lane]
  __shared__ __align__(16) u16 hstage[256];           // [r15][hcl] packed h
  const int tid = threadIdx.x;
  const int lane = tid & 63;
  const int w = tid >> 6;          // wave = K-quarter
  const int q = lane >> 4;
  const int r15 = lane & 15;
  const int j = blockIdx.x & 63;   // hc block (16 hidden units)
  const int bq = blockIdx.x >> 6;  // batch quarter (16 batches)
  const int b = bq * 16 + r15;

  // ---- A fragments (reg-resident): areg[t][kkl]
  // A[zrow = t*16 + r15][k = w*256 + kkl*32 + q*8 + jj],  zrow -> (hc,gate)
  const int gA = r15 & 3;
  const float* Vm = (gA == 0) ? V0 : (gA == 1) ? V1 : (gA == 2) ? V2 : V3;
  bf16x8 areg[4][8];
#pragma unroll
  for (int t = 0; t < 4; ++t) {
    const int hcA = j * 16 + t * 4 + (r15 >> 2);
    const float* Vcol = Vm + hcA;
#pragma unroll
    for (int kkl = 0; kkl < 8; ++kkl) {
      union { bf16x8 v; u16 s[8]; } au;
      const int k0 = w * 256 + kkl * 32 + q * 8;
#pragma unroll
      for (int jj = 0; jj < 8; ++jj)
        au.s[jj] = f2bf(Vcol[(size_t)(k0 + jj) * 1024]);
      areg[t][kkl] = au.v;
    }
  }

  // lane identity for gates/store: owns (b, hc), 4 gates in acc regs
  const int hcl = w * 4 + q;
  const int hc = j * 16 + hcl;
  const long long xpbase = (long long)hc * TBROWS * 4;
  // consumer h-load element offset within a slot ([jb][b][16] layout)
  const int laneoff = (w * 16 + (q >> 1)) * 1024 + b * 16 + (q & 1) * 8;
  const int* fp = flags + (bq * 64 + w * 16 + r15) * 32;   // spread flags (128B)
  float c = 0.0f;

  u32x2 xpv, xpn;
  // prologue: xp row for it=0 (non-temporal: read-once stream)
  {
    const u16* p0 = xp + xpbase + (long long)b * 4;
    asm volatile("global_load_dwordx2 %0, %1, off nt" : "=v"(xpv) : "v"(p0) : "memory");
    asm volatile("s_waitcnt vmcnt(0)" ::: "memory");
    __builtin_amdgcn_sched_barrier(0);
  }

#pragma unroll 1
  for (int it = 0; it < 512; ++it) {
    u32x4 hb[8];
    if (it > 0) {
      const u16* hpl = hseq + (size_t)(it - 1) * 65536 + laneoff;
      int fr0 = 0, fr1 = 0, fr2 = 0, fr3 = 0, fr4 = 0, fr5 = 0, fr6 = 0, fr7 = 0;
      // SPECULATIVE first pass: data loads overlap the flag propagation.
#define LOADV(i) if (!fr##i) \
      asm volatile("global_load_dwordx4 %0, %1, off sc0 sc1" \
                   : "=v"(hb[i]) : "v"(hpl + i * 2048) : "memory");
#define CHECKV(i) if (!fr##i) fr##i = __all(vec_fresh(hb[i]));
      LOADV(0) LOADV(1) LOADV(2) LOADV(3) LOADV(4) LOADV(5) LOADV(6) LOADV(7)
      asm volatile("s_waitcnt vmcnt(0)" ::: "memory");
      __builtin_amdgcn_sched_barrier(0);
      CHECKV(0) CHECKV(1) CHECKV(2) CHECKV(3) CHECKV(4) CHECKV(5) CHECKV(6) CHECKV(7)
      if (!(fr0 && fr1 && fr2 && fr3 && fr4 && fr5 && fr6 && fr7)) {
        // slow-producer path: flag-gate, then bounded re-read of stale subset
        int fbudget = 1 << 15;
#pragma unroll 1
        while (__hip_atomic_load(fp, __ATOMIC_RELAXED, __HIP_MEMORY_SCOPE_AGENT) < it) {
          if (--fbudget < 0) break;
        }
        int dbudget = 1 << 12;
#pragma unroll 1
        for (;;) {
          LOADV(0) LOADV(1) LOADV(2) LOADV(3) LOADV(4) LOADV(5) LOADV(6) LOADV(7)
          asm volatile("s_waitcnt vmcnt(0)" ::: "memory");
          __builtin_amdgcn_sched_barrier(0);
          CHECKV(0) CHECKV(1) CHECKV(2) CHECKV(3) CHECKV(4) CHECKV(5) CHECKV(6) CHECKV(7)
          if (fr0 && fr1 && fr2 && fr3 && fr4 && fr5 && fr6 && fr7) break;
          if (--dbudget < 0) break;   // fail fast, never hang
        }
      }
#undef LOADV
#undef CHECKV
      // xpn (prefetched last iteration) is drained by the pass's vmcnt(0);
      // fence reg-moves from hoisting above it (rule 18), then consume.
      __builtin_amdgcn_sched_barrier(0);
      xpv = xpn;
    }

    // issue next xp row (nt; drained by next iteration's first-pass vmcnt(0))
    if (it < 511) {
      const long long tbn = (long long)(it + 1 < 511 ? it + 1 : 510) * 64 + b;
      const u16* pn = xp + xpbase + tbn * 4;
      asm volatile("global_load_dwordx2 %0, %1, off nt" : "=v"(xpn) : "v"(pn) : "memory");
    }

    f32x4 acc[4];
#pragma unroll
    for (int t = 0; t < 4; ++t) acc[t] = (f32x4){0.f, 0.f, 0.f, 0.f};
    if (it > 0) {
#pragma unroll
      for (int kkl = 0; kkl < 8; ++kkl) {
        union { u32x4 u; bf16x8 v; } bu; bu.u = hb[kkl];
#pragma unroll
        for (int t = 0; t < 4; ++t)
          acc[t] = __builtin_amdgcn_mfma_f32_16x16x32_bf16(areg[t][kkl], bu.v,
                                                           acc[t], 0, 0, 0);
      }
    }

    // cross-wave K-reduction via LDS (parity double-buffered, one barrier)
    const int par = it & 1;
#pragma unroll
    for (int t = 0; t < 4; ++t) part[par][w][t][lane] = acc[t];
    __syncthreads();
    f32x4 z4 = part[par][0][w][lane];
#pragma unroll
    for (int pw = 1; pw < 4; ++pw) z4 += part[par][pw][w][lane];

    const float zi = z4[0] + bf2f((u16)(xpv[0] & 0xffff));
    const float zf = z4[1] + bf2f((u16)(xpv[0] >> 16));
    const float zg = z4[2] + bf2f((u16)(xpv[1] & 0xffff));
    const float zo = z4[3] + bf2f((u16)(xpv[1] >> 16));
    const float gi = fsigmoid(zi), gf = fsigmoid(zf);
    const float gg = ftanh(zg), go = fsigmoid(zo);
    c = gf * c + gi * gg;
    const float h = go * ftanh(c);

    if (it == 511) {
      out[(size_t)b * 1024 + hc] = h;
    } else {
      u32 hv = (u32)f2bf(h);
      // liveness clamp: no stored value may alias the sentinel range
      if (hv >= 0xC000u) hv = 0xBF80u;   // only reachable if h were -NaN
      hstage[r15 * 16 + hcl] = (u16)hv;
      __syncthreads();
      if (tid < 32) {
        const u32x4 pv = *(const u32x4*)&hstage[tid * 8];
        u16* dst = hseq + (size_t)it * 65536 + j * 1024 + bq * 256 + tid * 8;
        asm volatile("global_store_dwordx4 %0, %1, off sc0 sc1"
                     :: "v"(dst), "v"(pv) : "memory");
      }
      // early flag (R17-proven): same-wave program order after packed stores
      if (tid == 0)
        __hip_atomic_store(flags + (bq * 64 + j) * 32, it + 1,
                           __ATOMIC_RELAXED, __HIP_MEMORY_SCOPE_AGENT);
      // hstage/part reuse protection only (off the publish critical path)
      __builtin_amdgcn_s_barrier();
    }
  }
}

// ---------------- launch ----------------
extern "C" void kernel_launch(void* const* d_in, const int* in_sizes, int n_in,
                              void* d_out, int out_size, void* d_ws, size_t ws_size,
                              hipStream_t stream) {
  const float* x  = (const float*)d_in[0];
  const float* Ui = (const float*)d_in[1];
  const float* Vi = (const float*)d_in[2];
  const float* bi = (const float*)d_in[3];
  const float* Uf = (const float*)d_in[4];
  const float* Vf = (const float*)d_in[5];
  const float* bf_ = (const float*)d_in[6];
  const float* Uc = (const float*)d_in[7];
  const float* Vc = (const float*)d_in[8];
  const float* bc = (const float*)d_in[9];
  const float* Uo = (const float*)d_in[10];
  const float* Vo = (const float*)d_in[11];
  const float* bo = (const float*)d_in[12];

  char* ws = (char*)d_ws;
  // flags 32KB @0 (spread 1/128B) | xb/hseq 64MB @1MB (aliased: xb consumed by
  // gemm, then re-sentineled as hseq) | UbT 8MB @65MB | bb 16KB @73MB |
  // xp 255.5MB @73MB+64KB
  int* flags = (int*)ws;
  u16* xb    = (u16*)(ws + (size_t)(1 << 20));
  u16* hseq  = (u16*)(ws + (size_t)(1 << 20));
  u16* UbT   = (u16*)(ws + (size_t)(1 << 20) + ((size_t)64 << 20));
  float* bb  = (float*)(ws + (size_t)(1 << 20) + ((size_t)72 << 20));
  u16* xp    = (u16*)(ws + (size_t)(1 << 20) + ((size_t)72 << 20) + (1 << 16));

  conv_x<<<4096, 256, 0, stream>>>(x, xb);
  conv_u<<<1024, 256, 0, stream>>>(Ui, Uf, Uc, Uo, UbT);
  conv_b<<<16, 256, 0, stream>>>(bi, bf_, bc, bo, bb);
  gemm_xproj<<<8192, 256, 0, stream>>>(xb, UbT, bb, xp);
  init_sent<<<2048, 256, 0, stream>>>((u32*)hseq, flags);
  lstm_rec<<<256, 256, 0, stream>>>(Vi, Vf, Vc, Vo, xp, hseq, flags, (float*)d_out);
}

// Round 19
// 1838.904 us; speedup vs baseline: 1.3036x; 1.3036x over previous
//
#include <hip/hip_runtime.h>
#include <stdint.h>

typedef unsigned short u16;
typedef unsigned int   u32;
typedef __bf16 bf16x8 __attribute__((ext_vector_type(8)));
typedef float  f32x4  __attribute__((ext_vector_type(4)));
typedef u16    u16x8  __attribute__((ext_vector_type(8)));
typedef u32    u32x2  __attribute__((ext_vector_type(2)));
typedef u32    u32x4  __attribute__((ext_vector_type(4)));

#define TBROWS 32704   // 511 * 64 valid (t,b) rows

__device__ __forceinline__ u16 f2bf(float f) {
  union { float f; u32 u; } v; v.f = f;
  u32 r = v.u + 0x7FFFu + ((v.u >> 16) & 1u);   // RNE
  return (u16)(r >> 16);
}
__device__ __forceinline__ float bf2f(u16 h) {
  union { u32 u; float f; } v; v.u = ((u32)h) << 16;
  return v.f;
}
__device__ __forceinline__ float fsigmoid(float x) {
  return 1.0f / (1.0f + exp2f(-1.44269504f * x));
}
__device__ __forceinline__ float ftanh(float x) {
  return 2.0f / (1.0f + exp2f(-2.88539008f * x)) - 1.0f;
}
__device__ __forceinline__ u32 pkmaxu16(u32 a, u32 b) {
  u32 d;
  asm("v_pk_max_u16 %0, %1, %2" : "=v"(d) : "v"(a), "v"(b));
  return d;
}
// valid h (|h|<1 -> u16 code <= 0xBF80); sentinel 0xFFFF. fresh <=> all halves < 0xC000
__device__ __forceinline__ int vec_fresh(u32x4 v) {
  u32 m = pkmaxu16(pkmaxu16(v[0], v[1]), pkmaxu16(v[2], v[3]));
  return (m < 0xC0000000u) && ((m << 16) < 0xC0000000u);
}

// ---------------- conversions ----------------

// x f32 [64][512][1024] -> bf16 same layout
__global__ __launch_bounds__(256) void conv_x(const float* __restrict__ x,
                                              u16* __restrict__ xb) {
  const int n4 = (64 * 512 * 1024) / 4;
  const float4* xv = (const float4*)x;
  for (int i = blockIdx.x * 256 + threadIdx.x; i < n4; i += 4096 * 256) {
    float4 v = xv[i];
    uint2 o;
    o.x = (u32)f2bf(v.x) | ((u32)f2bf(v.y) << 16);
    o.y = (u32)f2bf(v.z) | ((u32)f2bf(v.w) << 16);
    *(uint2*)(xb + (size_t)i * 4) = o;
  }
}

// Build UbT bf16 [4096][1024]: UbT[n][k] = U_g[k][hc], n = hc*4 + g (gate-interleaved)
__global__ __launch_bounds__(256) void conv_u(const float* __restrict__ U0,
                                              const float* __restrict__ U1,
                                              const float* __restrict__ U2,
                                              const float* __restrict__ U3,
                                              u16* __restrict__ UbT) {
  __shared__ float tile[64][65];
  const int bid = blockIdx.x;
  const int g = bid >> 8, kt = (bid >> 4) & 15, ht = bid & 15;
  const float* U = (g == 0) ? U0 : (g == 1) ? U1 : (g == 2) ? U2 : U3;
  const int t = threadIdx.x;
  const int c = t & 63, r0 = t >> 6;
#pragma unroll
  for (int rr = 0; rr < 64; rr += 4)
    tile[rr + r0][c] = U[(size_t)(kt * 64 + rr + r0) * 1024 + ht * 64 + c];
  __syncthreads();
  const int hcl = t >> 2, ks = t & 3;
  const int n = (ht * 64 + hcl) * 4 + g;
  u16x8 o0, o1;
#pragma unroll
  for (int ii = 0; ii < 8; ++ii) o0[ii] = f2bf(tile[ks * 16 + ii][hcl]);
#pragma unroll
  for (int ii = 0; ii < 8; ++ii) o1[ii] = f2bf(tile[ks * 16 + 8 + ii][hcl]);
  size_t base = (size_t)n * 1024 + kt * 64 + ks * 16;
  *(u16x8*)(UbT + base) = o0;
  *(u16x8*)(UbT + base + 8) = o1;
}

// bb f32 [4096] gate-interleaved + zero the spread flags (replay-safe)
__global__ __launch_bounds__(256) void conv_b(const float* __restrict__ b0,
                                              const float* __restrict__ b1,
                                              const float* __restrict__ b2,
                                              const float* __restrict__ b3,
                                              float* __restrict__ bb,
                                              int* __restrict__ flags) {
  if (blockIdx.x == 0) flags[threadIdx.x * 32] = 0;   // 256 flags, 128B apart
  int n = blockIdx.x * 256 + threadIdx.x;
  if (n < 4096) {
    int g = n & 3, hc = n >> 2;
    const float* B = (g == 0) ? b0 : (g == 1) ? b1 : (g == 2) ? b2 : b3;
    bb[n] = B[hc];
  }
}

// ---------------- phase 1: x_proj GEMM ----------------
// xp[hc][tb][g] = sum_k UbT[hc*4+g][k] * xb[tb][k] + bb  (bf16 out)
// XCD-aware grid swizzle (T1): each XCD sweeps full nt rows per tt.
__global__ __launch_bounds__(256, 2) void gemm_xproj(const u16* __restrict__ xb,
                                                     const u16* __restrict__ UbT,
                                                     const float* __restrict__ bb,
                                                     u16* __restrict__ xp) {
  __shared__ __align__(16) u16 As[128 * 32];
  __shared__ __align__(16) u16 Bs[128 * 32];
  const int tid = threadIdx.x;
  const int lane = tid & 63, w = tid >> 6;
  const int q = lane >> 4, r15 = lane & 15;
  const int bid = (blockIdx.x & 7) * 1024 + (blockIdx.x >> 3);  // bijective (8192=8*1024)
  const int nt = bid & 31;               // M (n) tile
  const int tt = bid >> 5;               // N (tb) tile
  const int n_base = nt * 128;
  const long long tb_base = (long long)tt * 128;
  const int mh = w & 1, nh = w >> 1;

  f32x4 acc[4][4];
#pragma unroll
  for (int a = 0; a < 4; ++a)
#pragma unroll
    for (int b2 = 0; b2 < 4; ++b2) acc[a][b2] = (f32x4){0.f, 0.f, 0.f, 0.f};

#pragma unroll 1
  for (int kb = 0; kb < 32; ++kb) {
    __syncthreads();
    const int k0 = kb * 32;
#pragma unroll
    for (int call = 0; call < 2; ++call) {
      const int chunk = call * 256 + w * 64 + lane;
      const int row = chunk >> 2, q4 = chunk & 3;
      const u16* ga = UbT + (size_t)(n_base + row) * 1024 + k0 + q4 * 8;
      __builtin_amdgcn_global_load_lds(
          (const __attribute__((address_space(1))) void*)ga,
          (__attribute__((address_space(3))) void*)(As + (call * 256 + w * 64) * 8),
          16, 0, 0);
      long long tbr = tb_base + row;
      if (tbr > TBROWS - 1) tbr = TBROWS - 1;
      const int xbrow = ((int)tbr & 63) * 512 + ((int)tbr >> 6);  // (b,t) -> x row
      const u16* gb = xb + (size_t)xbrow * 1024 + k0 + q4 * 8;
      __builtin_amdgcn_global_load_lds(
          (const __attribute__((address_space(1))) void*)gb,
          (__attribute__((address_space(3))) void*)(Bs + (call * 256 + w * 64) * 8),
          16, 0, 0);
    }
    __syncthreads();
    bf16x8 af[4], bfr[4];
#pragma unroll
    for (int m = 0; m < 4; ++m)
      af[m] = *(const bf16x8*)(As + ((mh * 64 + m * 16 + r15) * 32 + q * 8));
#pragma unroll
    for (int n2 = 0; n2 < 4; ++n2)
      bfr[n2] = *(const bf16x8*)(Bs + ((nh * 64 + n2 * 16 + r15) * 32 + q * 8));
#pragma unroll
    for (int m = 0; m < 4; ++m)
#pragma unroll
      for (int n2 = 0; n2 < 4; ++n2)
        acc[m][n2] = __builtin_amdgcn_mfma_f32_16x16x32_bf16(af[m], bfr[n2],
                                                             acc[m][n2], 0, 0, 0);
  }
#pragma unroll
  for (int m = 0; m < 4; ++m) {
    const int nrow = n_base + mh * 64 + m * 16 + q * 4;
    const float4 bias = *(const float4*)(bb + nrow);
    const long long hcb = (long long)(nrow >> 2) * TBROWS;
#pragma unroll
    for (int n2 = 0; n2 < 4; ++n2) {
      const long long tb = tb_base + nh * 64 + n2 * 16 + r15;
      if (tb < TBROWS) {
        const f32x4 v = acc[m][n2];
        uint2 pk;
        pk.x = (u32)f2bf(v[0] + bias.x) | ((u32)f2bf(v[1] + bias.y) << 16);
        pk.y = (u32)f2bf(v[2] + bias.z) | ((u32)f2bf(v[3] + bias.w) << 16);
        *(uint2*)(xp + (hcb + tb) * 4) = pk;
      }
    }
  }
}

// ---------------- phase 2: persistent recurrence ----------------
// R17 protocol (measured-best): flag-gate -> one-shot loads -> in-band
// sentinel validation (bounded retry); fire-and-forget packed publish +
// early flag. NEW: each block sentinel-fills ITS OWN publish region at
// kernel start (vmcnt-drained before any publish) -> init_sent kernel
// deleted. Custody-safe, replay-safe (fill precedes any flag raise).
// NO destination pre-touch (R15), NO consumer speculation (R18).
__global__ __launch_bounds__(256, 1) void lstm_rec(
    const float* __restrict__ V0, const float* __restrict__ V1,
    const float* __restrict__ V2, const float* __restrict__ V3,
    const u16* __restrict__ xp, u16* hseq, int* flags, float* __restrict__ out) {
  __shared__ __align__(16) f32x4 part[2][4][4][64];   // [parity][wave][tile][lane]
  __shared__ __align__(16) u16 hstage[256];           // [r15][hcl] packed h
  const int tid = threadIdx.x;
  const int lane = tid & 63;
  const int w = tid >> 6;          // wave = K-quarter
  const int q = lane >> 4;
  const int r15 = lane & 15;
  const int j = blockIdx.x & 63;   // hc block (16 hidden units)
  const int bq = blockIdx.x >> 6;  // batch quarter (16 batches)
  const int b = bq * 16 + r15;

  // ---- sentinel-fill own publish region: 511 slots x 512B (custody-safe).
  // Drained by the vmcnt(0) below, BEFORE any publish/flag this call.
  {
    const u32x4 s = {~0u, ~0u, ~0u, ~0u};
#pragma unroll 1
    for (int i = tid; i < 16352; i += 256) {
      u16* p = hseq + (size_t)(i >> 5) * 65536 + j * 1024 + bq * 256 + (i & 31) * 8;
      asm volatile("global_store_dwordx4 %0, %1, off sc0 sc1"
                   :: "v"(p), "v"(s) : "memory");
    }
  }

  // ---- A fragments (reg-resident): areg[t][kkl]
  // A[zrow = t*16 + r15][k = w*256 + kkl*32 + q*8 + jj],  zrow -> (hc,gate)
  const int gA = r15 & 3;
  const float* Vm = (gA == 0) ? V0 : (gA == 1) ? V1 : (gA == 2) ? V2 : V3;
  bf16x8 areg[4][8];
#pragma unroll
  for (int t = 0; t < 4; ++t) {
    const int hcA = j * 16 + t * 4 + (r15 >> 2);
    const float* Vcol = Vm + hcA;
#pragma unroll
    for (int kkl = 0; kkl < 8; ++kkl) {
      union { bf16x8 v; u16 s[8]; } au;
      const int k0 = w * 256 + kkl * 32 + q * 8;
#pragma unroll
      for (int jj = 0; jj < 8; ++jj)
        au.s[jj] = f2bf(Vcol[(size_t)(k0 + jj) * 1024]);
      areg[t][kkl] = au.v;
    }
  }

  // lane identity for gates/store: owns (b, hc), 4 gates in acc regs
  const int hcl = w * 4 + q;
  const int hc = j * 16 + hcl;
  const long long xpbase = (long long)hc * TBROWS * 4;
  // consumer h-load element offset within a slot ([jb][b][16] layout)
  const int laneoff = (w * 16 + (q >> 1)) * 1024 + b * 16 + (q & 1) * 8;
  const int* fp = flags + (bq * 64 + w * 16 + r15) * 32;   // spread flags (128B)
  float c = 0.0f;

  u32x2 xpv, xpn;
  // prologue: xp row for it=0 (nt). The vmcnt(0) also drains the sentinel fill.
  {
    const u16* p0 = xp + xpbase + (long long)b * 4;
    asm volatile("global_load_dwordx2 %0, %1, off nt" : "=v"(xpv) : "v"(p0) : "memory");
    asm volatile("s_waitcnt vmcnt(0)" ::: "memory");
    __builtin_amdgcn_sched_barrier(0);
  }

#pragma unroll 1
  for (int it = 0; it < 512; ++it) {
    u32x4 hb[8];
    if (it > 0) {
      // per-wave flag wait (no block barrier, no sleep)
      int fbudget = 1 << 15;
#pragma unroll 1
      while (__hip_atomic_load(fp, __ATOMIC_RELAXED, __HIP_MEMORY_SCOPE_AGENT) < it) {
        if (--fbudget < 0) break;
      }
      // one-shot loads + in-band sentinel validation (re-load only stale)
      const u16* hpl = hseq + (size_t)(it - 1) * 65536 + laneoff;
      int fr0 = 0, fr1 = 0, fr2 = 0, fr3 = 0, fr4 = 0, fr5 = 0, fr6 = 0, fr7 = 0;
      int dbudget = 1 << 12;
#pragma unroll 1
      for (;;) {
#define LOADV(i) if (!fr##i) \
        asm volatile("global_load_dwordx4 %0, %1, off sc0 sc1" \
                     : "=v"(hb[i]) : "v"(hpl + i * 2048) : "memory");
        LOADV(0) LOADV(1) LOADV(2) LOADV(3) LOADV(4) LOADV(5) LOADV(6) LOADV(7)
#undef LOADV
        asm volatile("s_waitcnt vmcnt(0)" ::: "memory");
        __builtin_amdgcn_sched_barrier(0);
#define CHECKV(i) if (!fr##i) fr##i = __all(vec_fresh(hb[i]));
        CHECKV(0) CHECKV(1) CHECKV(2) CHECKV(3) CHECKV(4) CHECKV(5) CHECKV(6) CHECKV(7)
#undef CHECKV
        if (fr0 && fr1 && fr2 && fr3 && fr4 && fr5 && fr6 && fr7) break;
        if (--dbudget < 0) break;   // fail fast, never hang
      }
      // xpn (prefetched last iteration) is drained by the loop's vmcnt(0);
      // fence reg-moves from hoisting above it (rule 18), then consume.
      __builtin_amdgcn_sched_barrier(0);
      xpv = xpn;
    }

    // issue next xp row (nt; drained by next iteration's validate-loop vmcnt(0))
    if (it < 511) {
      const long long tbn = (long long)(it + 1 < 511 ? it + 1 : 510) * 64 + b;
      const u16* pn = xp + xpbase + tbn * 4;
      asm volatile("global_load_dwordx2 %0, %1, off nt" : "=v"(xpn) : "v"(pn) : "memory");
    }

    f32x4 acc[4];
#pragma unroll
    for (int t = 0; t < 4; ++t) acc[t] = (f32x4){0.f, 0.f, 0.f, 0.f};
    if (it > 0) {
#pragma unroll
      for (int kkl = 0; kkl < 8; ++kkl) {
        union { u32x4 u; bf16x8 v; } bu; bu.u = hb[kkl];
#pragma unroll
        for (int t = 0; t < 4; ++t)
          acc[t] = __builtin_amdgcn_mfma_f32_16x16x32_bf16(areg[t][kkl], bu.v,
                                                           acc[t], 0, 0, 0);
      }
    }

    // cross-wave K-reduction via LDS (parity double-buffered, one barrier)
    const int par = it & 1;
#pragma unroll
    for (int t = 0; t < 4; ++t) part[par][w][t][lane] = acc[t];
    __syncthreads();
    f32x4 z4 = part[par][0][w][lane];
#pragma unroll
    for (int pw = 1; pw < 4; ++pw) z4 += part[par][pw][w][lane];

    const float zi = z4[0] + bf2f((u16)(xpv[0] & 0xffff));
    const float zf = z4[1] + bf2f((u16)(xpv[0] >> 16));
    const float zg = z4[2] + bf2f((u16)(xpv[1] & 0xffff));
    const float zo = z4[3] + bf2f((u16)(xpv[1] >> 16));
    const float gi = fsigmoid(zi), gf = fsigmoid(zf);
    const float gg = ftanh(zg), go = fsigmoid(zo);
    c = gf * c + gi * gg;
    const float h = go * ftanh(c);

    if (it == 511) {
      out[(size_t)b * 1024 + hc] = h;
    } else {
      u32 hv = (u32)f2bf(h);
      // liveness clamp: no stored value may alias the sentinel range
      if (hv >= 0xC000u) hv = 0xBF80u;   // only reachable if h were -NaN
      hstage[r15 * 16 + hcl] = (u16)hv;
      __syncthreads();
      if (tid < 32) {
        const u32x4 pv = *(const u32x4*)&hstage[tid * 8];
        u16* dst = hseq + (size_t)it * 65536 + j * 1024 + bq * 256 + tid * 8;
        asm volatile("global_store_dwordx4 %0, %1, off sc0 sc1"
                     :: "v"(dst), "v"(pv) : "memory");
      }
      // early flag (R17-proven): same-wave program order after packed stores
      if (tid == 0)
        __hip_atomic_store(flags + (bq * 64 + j) * 32, it + 1,
                           __ATOMIC_RELAXED, __HIP_MEMORY_SCOPE_AGENT);
      // hstage/part reuse protection only (off the publish critical path)
      __builtin_amdgcn_s_barrier();
    }
  }
}

// ---------------- launch ----------------
extern "C" void kernel_launch(void* const* d_in, const int* in_sizes, int n_in,
                              void* d_out, int out_size, void* d_ws, size_t ws_size,
                              hipStream_t stream) {
  const float* x  = (const float*)d_in[0];
  const float* Ui = (const float*)d_in[1];
  const float* Vi = (const float*)d_in[2];
  const float* bi = (const float*)d_in[3];
  const float* Uf = (const float*)d_in[4];
  const float* Vf = (const float*)d_in[5];
  const float* bf_ = (const float*)d_in[6];
  const float* Uc = (const float*)d_in[7];
  const float* Vc = (const float*)d_in[8];
  const float* bc = (const float*)d_in[9];
  const float* Uo = (const float*)d_in[10];
  const float* Vo = (const float*)d_in[11];
  const float* bo = (const float*)d_in[12];

  char* ws = (char*)d_ws;
  // flags 32KB @0 (spread 1/128B) | xb/hseq 64MB @1MB (aliased: xb consumed by
  // gemm, then self-sentineled as hseq inside lstm_rec) | UbT 8MB @65MB |
  // bb 16KB @73MB | xp 255.5MB @73MB+64KB
  int* flags = (int*)ws;
  u16* xb    = (u16*)(ws + (size_t)(1 << 20));
  u16* hseq  = (u16*)(ws + (size_t)(1 << 20));
  u16* UbT   = (u16*)(ws + (size_t)(1 << 20) + ((size_t)64 << 20));
  float* bb  = (float*)(ws + (size_t)(1 << 20) + ((size_t)72 << 20));
  u16* xp    = (u16*)(ws + (size_t)(1 << 20) + ((size_t)72 << 20) + (1 << 16));

  conv_x<<<4096, 256, 0, stream>>>(x, xb);
  conv_u<<<1024, 256, 0, stream>>>(Ui, Uf, Uc, Uo, UbT);
  conv_b<<<16, 256, 0, stream>>>(bi, bf_, bc, bo, bb, flags);
  gemm_xproj<<<8192, 256, 0, stream>>>(xb, UbT, bb, xp);
  lstm_rec<<<256, 256, 0, stream>>>(Vi, Vf, Vc, Vo, xp, hseq, flags, (float*)d_out);
}